// Round 3
// 498.642 us; speedup vs baseline: 1.1166x; 1.1166x over previous
//
#include <hip/hip_runtime.h>

typedef __attribute__((ext_vector_type(8))) short short8;
typedef __attribute__((ext_vector_type(4))) float f32x4;

#define B_    32
#define CI_   256
#define H_    56
#define HW_   3136     // 56*56
#define CO_   512
#define OHW_  54
#define PIXB_ 2916     // 54*54
#define NPIX_ 93312    // 32*2916

// ws layout: x_t bf16 [32][56][56][256]  = 51,380,224 B at offset 0
//            w_t bf16 [9][512][256]      =  2,359,296 B at offset 51,380,224
#define XT_BYTES 51380224ull
#define WS_NEED  53739520ull

__device__ __forceinline__ ushort f2bf(float f) {
  unsigned u = __float_as_uint(f);
  unsigned r = (u + 0x7FFFu + ((u >> 16) & 1u)) >> 16;  // RNE
  return (ushort)r;
}

__device__ __forceinline__ void async16(const void* g, void* l) {
  __builtin_amdgcn_global_load_lds(
      (const __attribute__((address_space(1))) unsigned int*)g,
      (__attribute__((address_space(3))) unsigned int*)l, 16, 0, 0);
}

// ---- pre-pass: x [b][ci][h][w] f32 -> x_t [b][h*w][ci] bf16 ------------
#define CIP 260
__global__ __launch_bounds__(256)
void transpose_x(const float* __restrict__ x, ushort* __restrict__ xt) {
  __shared__ ushort tile[64 * CIP];              // 33,280 B
  const int b = blockIdx.y, hw0 = blockIdx.x * 64;
  const int t = threadIdx.x;
  const int j = t & 15, q = t >> 4;              // j: hw4 group, q: ci4 group
  const int hw4 = j * 4;
  const float* xb = x + (size_t)b * CI_ * HW_ + hw0;

  #pragma unroll
  for (int p = 0; p < 4; ++p) {                  // 64 ci per pass
    const int c0 = p * 64 + q * 4;
    float4 v[4];
    #pragma unroll
    for (int r = 0; r < 4; ++r)
      v[r] = *(const float4*)(xb + (size_t)(c0 + r) * HW_ + hw4);
    #pragma unroll
    for (int r2 = 0; r2 < 4; ++r2) {             // r2 = hw offset
      ushort4 o;
      o.x = f2bf(((const float*)&v[0])[r2]);
      o.y = f2bf(((const float*)&v[1])[r2]);
      o.z = f2bf(((const float*)&v[2])[r2]);
      o.w = f2bf(((const float*)&v[3])[r2]);
      *(ushort4*)&tile[(hw4 + r2) * CIP + c0] = o;   // b64, conflict-free
    }
  }
  __syncthreads();

  ushort* ob = xt + ((size_t)b * HW_ + hw0) * CI_;
  #pragma unroll
  for (int p = 0; p < 8; ++p) {
    const int hw  = p * 8 + (t >> 5);
    const int ci8 = (t & 31) * 8;
    const ushort* src = &tile[hw * CIP + ci8];
    uint2 lo = *(const uint2*)src;
    uint2 hi = *(const uint2*)(src + 4);
    uint4 v; v.x = lo.x; v.y = lo.y; v.z = hi.x; v.w = hi.y;
    *(uint4*)(ob + (size_t)hw * CI_ + ci8) = v;  // 16B coalesced
  }
}

// ---- pre-pass: w [co][ci][kh][kw] f32 -> w_t [khkw][co][ci] bf16 -------
__global__ __launch_bounds__(256)
void repack_w(const float* __restrict__ w, ushort* __restrict__ wt) {
  __shared__ float buf[2304];
  const int co = blockIdx.x, t = threadIdx.x;
  const float* wp = w + (size_t)co * 2304;
  #pragma unroll
  for (int p = 0; p < 9; ++p) buf[p * 256 + t] = wp[p * 256 + t];
  __syncthreads();
  #pragma unroll
  for (int k = 0; k < 9; ++k)
    wt[(size_t)k * CO_ * CI_ + (size_t)co * CI_ + t] = f2bf(buf[t * 9 + k]);
}

// ---- main: implicit GEMM, 256co x 128pix tile, BK=64, 8 waves ----------
// Counted-vmcnt triple-buffered pipeline (T3+T4), raw s_barrier (no vmcnt
// drain), T2 XOR swizzle ((row&7)<<4) on 128B LDS rows via inverse-swizzled
// global source + swizzled ds_read, T5 setprio, bijective XCD chunk swizzle.
//   36 K-steps (9 taps x 4 ci-chunks of 64); per step: 2 phases x 16 MFMA.
//   Stage 6 x global_load_lds per step for tile t+2; vmcnt(6) at step top.
#define NT_    36
#define BUFSZ_ 49152          // A 32KB + B 16KB
#define BOFF_  32768
#define NBLK_  1458           // 729 pixel strips x 2 co halves

__global__ __launch_bounds__(512, 2)
void conv_mfma(const ushort* __restrict__ xt, const ushort* __restrict__ wt,
               float* __restrict__ out) {
  __shared__ __align__(128) char lds[3 * BUFSZ_];   // 144 KiB, 1 block/CU

  const int tid  = threadIdx.x;
  const int l    = tid & 63;
  const int wv   = tid >> 6;
  const int quad = l >> 4;
  const int l16  = l & 15;
  const int lr   = l >> 3;          // row-within-8 for staging
  const int lc   = l & 7;           // 16B chunk within 128B row
  const int cswz = (lc ^ lr) << 3;  // ushort offset: inverse-swizzled source

  // bijective XCD chunking (m204; nwg=1458 -> q=182,r=2), co-fastest inside
  const int q8 = 182, r8 = 2;
  const int xcd = blockIdx.x & 7;
  const int idx = blockIdx.x >> 3;
  const int logical =
      (xcd < r8 ? xcd * (q8 + 1) : r8 * (q8 + 1) + (xcd - r8) * q8) + idx;
  const int co0 = (logical & 1) << 8;     // 0 or 256
  const int P0  = (logical >> 1) << 7;    // pixel strip * 128

  // staging source bases (per-thread constants)
  const size_t wbaseA = (size_t)(co0 + wv * 8 + lr) * CI_ + cswz;
  size_t xbase[2];
  #pragma unroll
  for (int r = 0; r < 2; ++r) {
    int P = P0 + r * 64 + wv * 8 + lr;
    int b = P / PIXB_; int rem = P - b * PIXB_;
    int oh = rem / OHW_; int ow = rem - oh * OHW_;
    xbase[r] = ((size_t)b * HW_ + oh * H_ + ow) * CI_ + cswz;
  }

  // fragment read offsets: physical = logical ^ ((row&7)<<4); row&7 == l16&7
  const int wm  = (wv & 3) << 6;    // co offset in 256
  const int wn  = (wv >> 2) << 6;   // pix offset in 128
  const int sA0 = (quad << 4) ^ ((l16 & 7) << 4);
  int raoff[4], rboff[4];
  #pragma unroll
  for (int i = 0; i < 4; ++i) {
    raoff[i] = (wm + i * 16 + l16) * 128 + sA0;
    rboff[i] = BOFF_ + (wn + i * 16 + l16) * 128 + sA0;
  }

  f32x4 acc[4][4];
  #pragma unroll
  for (int i = 0; i < 4; ++i)
    #pragma unroll
    for (int j = 0; j < 4; ++j) acc[i][j] = (f32x4){0.f, 0.f, 0.f, 0.f};

  // stage helpers: tile tt -> buffer buf. A: rounds r0,r0+1; B: round r.
  auto issueA2 = [&](int buf, int tt, int r0) {
    const int k2 = tt >> 2; const int c2 = (tt & 3) << 6;
    const ushort* src = wt + (size_t)k2 * (CO_ * CI_) + wbaseA + c2;
    char* dst = lds + buf * BUFSZ_ + wv * 1024;
    async16(src + (size_t)(r0 << 6) * CI_,       dst + r0 * 8192);
    async16(src + (size_t)((r0 + 1) << 6) * CI_, dst + (r0 + 1) * 8192);
  };
  auto issueB1 = [&](int buf, int tt, int r) {
    const int k2 = tt >> 2; const int c2 = (tt & 3) << 6;
    const int kh2 = k2 / 3, kw2 = k2 - kh2 * 3;
    async16(xt + xbase[r] + (size_t)(kh2 * H_ + kw2) * CI_ + c2,
            lds + buf * BUFSZ_ + BOFF_ + r * 8192 + wv * 1024);
  };

  // prologue: tiles 0,1 fully staged (12 loads/wave in flight)
  issueA2(0, 0, 0); issueA2(0, 0, 2); issueB1(0, 0, 0); issueB1(0, 0, 1);
  issueA2(1, 1, 0); issueA2(1, 1, 2); issueB1(1, 1, 0); issueB1(1, 1, 1);

  int cur = 0;
  for (int t = 0; t < NT_; ++t) {
    // tile t's 6 loads landed; tile t+1's 6 may stay in flight
    if (t == NT_ - 1) asm volatile("s_waitcnt vmcnt(0)" ::: "memory");
    else              asm volatile("s_waitcnt vmcnt(6)" ::: "memory");
    __builtin_amdgcn_sched_barrier(0);     // pin: nothing crosses the wait
    __builtin_amdgcn_s_barrier();          // buf[cur] visible to all waves
    asm volatile("" ::: "memory");

    const char* ab  = lds + cur * BUFSZ_;
    const int ibuf  = (cur == 0) ? 2 : cur - 1;   // (t+2) % 3
    const bool pf   = (t < NT_ - 2);

    // ---- phase A: k = 0..31 of this 64-chunk
    short8 af[4], bfr[4];
    #pragma unroll
    for (int i = 0; i < 4; ++i) {
      af[i]  = *(const short8*)(ab + raoff[i]);
      bfr[i] = *(const short8*)(ab + rboff[i]);
    }
    if (pf) { issueA2(ibuf, t + 2, 0); issueB1(ibuf, t + 2, 0); }
    asm volatile("" ::: "memory");
    __builtin_amdgcn_s_barrier();          // phase gate (role split)
    asm volatile("" ::: "memory");
    __builtin_amdgcn_s_setprio(1);
    #pragma unroll
    for (int mt = 0; mt < 4; ++mt)
      #pragma unroll
      for (int nt = 0; nt < 4; ++nt)
        acc[mt][nt] = __builtin_amdgcn_mfma_f32_16x16x32_bf16(
            af[mt], bfr[nt], acc[mt][nt], 0, 0, 0);
    __builtin_amdgcn_s_setprio(0);

    // ---- phase B: k = 32..63 (physical offset ^64: swizzle keeps bit6)
    #pragma unroll
    for (int i = 0; i < 4; ++i) {
      af[i]  = *(const short8*)(ab + (raoff[i] ^ 64));
      bfr[i] = *(const short8*)(ab + (rboff[i] ^ 64));
    }
    if (pf) { issueA2(ibuf, t + 2, 2); issueB1(ibuf, t + 2, 1); }
    asm volatile("" ::: "memory");
    __builtin_amdgcn_s_barrier();
    asm volatile("" ::: "memory");
    __builtin_amdgcn_s_setprio(1);
    #pragma unroll
    for (int mt = 0; mt < 4; ++mt)
      #pragma unroll
      for (int nt = 0; nt < 4; ++nt)
        acc[mt][nt] = __builtin_amdgcn_mfma_f32_16x16x32_bf16(
            af[mt], bfr[nt], acc[mt][nt], 0, 0, 0);
    __builtin_amdgcn_s_setprio(0);

    cur = (cur == 2) ? 0 : cur + 1;
  }

  // epilogue: D row = co (quad*4+reg), col = pixel (lane&15)
  #pragma unroll
  for (int nt = 0; nt < 4; ++nt) {
    int P = P0 + wn + nt * 16 + l16;
    int b = P / PIXB_; int rem = P - b * PIXB_;
    size_t obase = (size_t)b * (CO_ * PIXB_) + rem;
    #pragma unroll
    for (int mt = 0; mt < 4; ++mt) {
      int cobase = co0 + wm + mt * 16 + quad * 4;
      #pragma unroll
      for (int r = 0; r < 4; ++r)
        out[obase + (size_t)(cobase + r) * PIXB_] = acc[mt][nt][r];
    }
  }
}

// ---- fallback: direct conv (only if ws too small) ----------------------
__global__ void naive_conv(const float* __restrict__ x, const float* __restrict__ w,
                           float* __restrict__ out) {
  size_t i = (size_t)blockIdx.x * 256 + threadIdx.x;
  if (i >= (size_t)47775744ull) return;
  int ow = (int)(i % OHW_); size_t r = i / OHW_;
  int oh = (int)(r % OHW_); r /= OHW_;
  int co = (int)(r % CO_);  int b = (int)(r / CO_);
  const float* xp = x + (size_t)b * CI_ * HW_;
  const float* wp = w + (size_t)co * CI_ * 9;
  float acc = 0.f;
  for (int ci = 0; ci < CI_; ++ci) {
    const float* xr = xp + (size_t)ci * HW_ + oh * H_ + ow;
    const float* wr = wp + ci * 9;
    #pragma unroll
    for (int kh = 0; kh < 3; ++kh)
      #pragma unroll
      for (int kw = 0; kw < 3; ++kw)
        acc += xr[kh * H_ + kw] * wr[kh * 3 + kw];
  }
  out[i] = acc;
}

extern "C" void kernel_launch(void* const* d_in, const int* in_sizes, int n_in,
                              void* d_out, int out_size, void* d_ws, size_t ws_size,
                              hipStream_t stream) {
  const float* x = (const float*)d_in[0];
  const float* w = (const float*)d_in[1];
  float* out = (float*)d_out;

  if (ws_size >= WS_NEED) {
    ushort* xt = (ushort*)d_ws;
    ushort* wt = (ushort*)((char*)d_ws + XT_BYTES);
    transpose_x<<<dim3(49, 32), 256, 0, stream>>>(x, xt);
    repack_w<<<dim3(512), 256, 0, stream>>>(w, wt);
    conv_mfma<<<dim3(NBLK_), 512, 0, stream>>>(xt, wt, out);
  } else {
    naive_conv<<<(47775744 + 255) / 256, 256, 0, stream>>>(x, w, out);
  }
}

// Round 4
// 492.089 us; speedup vs baseline: 1.1314x; 1.0133x over previous
//
#include <hip/hip_runtime.h>

typedef __attribute__((ext_vector_type(8))) short short8;
typedef __attribute__((ext_vector_type(4))) float f32x4;

#define B_    32
#define CI_   256
#define H_    56
#define HW_   3136     // 56*56
#define CO_   512
#define OHW_  54
#define PIXB_ 2916     // 54*54
#define NPIX_ 93312    // 32*2916

// ws layout: x_t bf16 [32][56][56][256]  = 51,380,224 B at offset 0
//            w_t bf16 [9][512][256]      =  2,359,296 B at offset 51,380,224
#define XT_BYTES 51380224ull
#define WS_NEED  53739520ull

__device__ __forceinline__ ushort f2bf(float f) {
  unsigned u = __float_as_uint(f);
  unsigned r = (u + 0x7FFFu + ((u >> 16) & 1u)) >> 16;  // RNE
  return (ushort)r;
}

__device__ __forceinline__ void async16(const void* g, void* l) {
  __builtin_amdgcn_global_load_lds(
      (const __attribute__((address_space(1))) unsigned int*)g,
      (__attribute__((address_space(3))) unsigned int*)l, 16, 0, 0);
}

// ---- pre-pass: x [b][ci][h][w] f32 -> x_t [b][h*w][ci] bf16 ------------
// v2: 64hw x 128ci tile (16.9KB LDS -> 9 blocks/CU, was 4), grid x2.
// Stores remain 256B-contiguous per hw row (fully coalesced at 64B grain).
#define CIP2 132
__global__ __launch_bounds__(256)
void transpose_x(const float* __restrict__ x, ushort* __restrict__ xt) {
  __shared__ ushort tile[64 * CIP2];             // 16,896 B
  const int b = blockIdx.y, hw0 = blockIdx.x * 64, ci0 = blockIdx.z * 128;
  const int t = threadIdx.x;
  const int j = t & 15, q = t >> 4;              // j: hw4 group, q: ci4 group
  const int hw4 = j * 4;
  const float* xb = x + ((size_t)b * CI_ + ci0) * HW_ + hw0;

  #pragma unroll
  for (int p = 0; p < 2; ++p) {                  // 64 ci per pass
    const int c0 = p * 64 + q * 4;
    float4 v[4];
    #pragma unroll
    for (int r = 0; r < 4; ++r)
      v[r] = *(const float4*)(xb + (size_t)(c0 + r) * HW_ + hw4);
    #pragma unroll
    for (int r2 = 0; r2 < 4; ++r2) {             // r2 = hw offset
      ushort4 o;
      o.x = f2bf(((const float*)&v[0])[r2]);
      o.y = f2bf(((const float*)&v[1])[r2]);
      o.z = f2bf(((const float*)&v[2])[r2]);
      o.w = f2bf(((const float*)&v[3])[r2]);
      *(ushort4*)&tile[(hw4 + r2) * CIP2 + c0] = o;   // b64
    }
  }
  __syncthreads();

  ushort* ob = xt + ((size_t)b * HW_ + hw0) * CI_ + ci0;
  #pragma unroll
  for (int p = 0; p < 4; ++p) {
    const int hw  = p * 16 + (t >> 4);
    const int ci8 = (t & 15) * 8;
    const ushort* src = &tile[hw * CIP2 + ci8];
    uint2 lo = *(const uint2*)src;               // rows at 264B: 8B-aligned
    uint2 hi = *(const uint2*)(src + 4);
    uint4 v; v.x = lo.x; v.y = lo.y; v.z = hi.x; v.w = hi.y;
    *(uint4*)(ob + (size_t)hw * CI_ + ci8) = v;  // 256B/row, coalesced
  }
}

// ---- pre-pass: w [co][ci][kh][kw] f32 -> w_t [khkw][co][ci] bf16 -------
__global__ __launch_bounds__(256)
void repack_w(const float* __restrict__ w, ushort* __restrict__ wt) {
  __shared__ float buf[2304];
  const int co = blockIdx.x, t = threadIdx.x;
  const float* wp = w + (size_t)co * 2304;
  #pragma unroll
  for (int p = 0; p < 9; ++p) buf[p * 256 + t] = wp[p * 256 + t];
  __syncthreads();
  #pragma unroll
  for (int k = 0; k < 9; ++k)
    wt[(size_t)k * CO_ * CI_ + (size_t)co * CI_ + t] = f2bf(buf[t * 9 + k]);
}

// ---- main: implicit GEMM, 256co x 128pix tile, BK=64, 8 waves ----------
// Counted-vmcnt triple-buffered pipeline; ONE barrier per K-step (the
// phase-gate barriers are gone: with 1 block/CU they forced LDS-read and
// MFMA to alternate; the top barrier alone protects the triple-buffer WAR,
// so waves may desync within a step and overlap ds_read with MFMA).
#define NT_    36
#define BUFSZ_ 49152          // A 32KB + B 16KB
#define BOFF_  32768
#define NBLK_  1458           // 729 pixel strips x 2 co halves

__global__ __launch_bounds__(512, 2)
void conv_mfma(const ushort* __restrict__ xt, const ushort* __restrict__ wt,
               float* __restrict__ out) {
  __shared__ __align__(128) char lds[3 * BUFSZ_];   // 144 KiB, 1 block/CU

  const int tid  = threadIdx.x;
  const int l    = tid & 63;
  const int wv   = tid >> 6;
  const int quad = l >> 4;
  const int l16  = l & 15;
  const int lr   = l >> 3;          // row-within-8 for staging
  const int lc   = l & 7;           // 16B chunk within 128B row
  const int cswz = (lc ^ lr) << 3;  // ushort offset: inverse-swizzled source

  // bijective XCD chunking (m204; nwg=1458 -> q=182,r=2), co-fastest inside
  const int q8 = 182, r8 = 2;
  const int xcd = blockIdx.x & 7;
  const int idx = blockIdx.x >> 3;
  const int logical =
      (xcd < r8 ? xcd * (q8 + 1) : r8 * (q8 + 1) + (xcd - r8) * q8) + idx;
  const int co0 = (logical & 1) << 8;     // 0 or 256
  const int P0  = (logical >> 1) << 7;    // pixel strip * 128

  // staging source bases (per-thread constants)
  const size_t wbaseA = (size_t)(co0 + wv * 8 + lr) * CI_ + cswz;
  size_t xbase[2];
  #pragma unroll
  for (int r = 0; r < 2; ++r) {
    int P = P0 + r * 64 + wv * 8 + lr;
    int b = P / PIXB_; int rem = P - b * PIXB_;
    int oh = rem / OHW_; int ow = rem - oh * OHW_;
    xbase[r] = ((size_t)b * HW_ + oh * H_ + ow) * CI_ + cswz;
  }

  // fragment read offsets: physical = logical ^ ((row&7)<<4); row&7 == l16&7
  const int wm  = (wv & 3) << 6;    // co offset in 256
  const int wn  = (wv >> 2) << 6;   // pix offset in 128
  const int sA0 = (quad << 4) ^ ((l16 & 7) << 4);
  int raoff[4], rboff[4];
  #pragma unroll
  for (int i = 0; i < 4; ++i) {
    raoff[i] = (wm + i * 16 + l16) * 128 + sA0;
    rboff[i] = BOFF_ + (wn + i * 16 + l16) * 128 + sA0;
  }

  f32x4 acc[4][4];
  #pragma unroll
  for (int i = 0; i < 4; ++i)
    #pragma unroll
    for (int j = 0; j < 4; ++j) acc[i][j] = (f32x4){0.f, 0.f, 0.f, 0.f};

  // stage helpers: tile tt -> buffer buf. A: rounds r0,r0+1; B: round r.
  auto issueA2 = [&](int buf, int tt, int r0) {
    const int k2 = tt >> 2; const int c2 = (tt & 3) << 6;
    const ushort* src = wt + (size_t)k2 * (CO_ * CI_) + wbaseA + c2;
    char* dst = lds + buf * BUFSZ_ + wv * 1024;
    async16(src + (size_t)(r0 << 6) * CI_,       dst + r0 * 8192);
    async16(src + (size_t)((r0 + 1) << 6) * CI_, dst + (r0 + 1) * 8192);
  };
  auto issueB1 = [&](int buf, int tt, int r) {
    const int k2 = tt >> 2; const int c2 = (tt & 3) << 6;
    const int kh2 = k2 / 3, kw2 = k2 - kh2 * 3;
    async16(xt + xbase[r] + (size_t)(kh2 * H_ + kw2) * CI_ + c2,
            lds + buf * BUFSZ_ + BOFF_ + r * 8192 + wv * 1024);
  };

  // prologue: tiles 0,1 fully staged (12 loads/wave in flight)
  issueA2(0, 0, 0); issueA2(0, 0, 2); issueB1(0, 0, 0); issueB1(0, 0, 1);
  issueA2(1, 1, 0); issueA2(1, 1, 2); issueB1(1, 1, 0); issueB1(1, 1, 1);

  int cur = 0;
  for (int t = 0; t < NT_; ++t) {
    // tile t's 6 loads landed; tile t+1's 6 may stay in flight
    if (t == NT_ - 1) asm volatile("s_waitcnt vmcnt(0)" ::: "memory");
    else              asm volatile("s_waitcnt vmcnt(6)" ::: "memory");
    __builtin_amdgcn_sched_barrier(0);     // pin: nothing crosses the wait
    __builtin_amdgcn_s_barrier();          // buf[cur] visible; prev reads done
    asm volatile("" ::: "memory");

    const char* ab  = lds + cur * BUFSZ_;
    const int ibuf  = (cur == 0) ? 2 : cur - 1;   // (t+2) % 3
    const bool pf   = (t < NT_ - 2);

    // ---- phase A: k = 0..31 of this 64-chunk
    short8 af[4], bfr[4];
    #pragma unroll
    for (int i = 0; i < 4; ++i) {
      af[i]  = *(const short8*)(ab + raoff[i]);
      bfr[i] = *(const short8*)(ab + rboff[i]);
    }
    if (pf) { issueA2(ibuf, t + 2, 0); issueB1(ibuf, t + 2, 0); }
    __builtin_amdgcn_s_setprio(1);
    #pragma unroll
    for (int mt = 0; mt < 4; ++mt)
      #pragma unroll
      for (int nt = 0; nt < 4; ++nt)
        acc[mt][nt] = __builtin_amdgcn_mfma_f32_16x16x32_bf16(
            af[mt], bfr[nt], acc[mt][nt], 0, 0, 0);
    __builtin_amdgcn_s_setprio(0);

    // ---- phase B: k = 32..63 (physical offset ^64: swizzle keeps bit6)
    #pragma unroll
    for (int i = 0; i < 4; ++i) {
      af[i]  = *(const short8*)(ab + (raoff[i] ^ 64));
      bfr[i] = *(const short8*)(ab + (rboff[i] ^ 64));
    }
    if (pf) { issueA2(ibuf, t + 2, 2); issueB1(ibuf, t + 2, 1); }
    __builtin_amdgcn_s_setprio(1);
    #pragma unroll
    for (int mt = 0; mt < 4; ++mt)
      #pragma unroll
      for (int nt = 0; nt < 4; ++nt)
        acc[mt][nt] = __builtin_amdgcn_mfma_f32_16x16x32_bf16(
            af[mt], bfr[nt], acc[mt][nt], 0, 0, 0);
    __builtin_amdgcn_s_setprio(0);

    cur = (cur == 2) ? 0 : cur + 1;
  }

  // epilogue: D row = co (quad*4+reg), col = pixel (lane&15)
  #pragma unroll
  for (int nt = 0; nt < 4; ++nt) {
    int P = P0 + wn + nt * 16 + l16;
    int b = P / PIXB_; int rem = P - b * PIXB_;
    size_t obase = (size_t)b * (CO_ * PIXB_) + rem;
    #pragma unroll
    for (int mt = 0; mt < 4; ++mt) {
      int cobase = co0 + wm + mt * 16 + quad * 4;
      #pragma unroll
      for (int r = 0; r < 4; ++r)
        out[obase + (size_t)(cobase + r) * PIXB_] = acc[mt][nt][r];
    }
  }
}

// ---- fallback: direct conv (only if ws too small) ----------------------
__global__ void naive_conv(const float* __restrict__ x, const float* __restrict__ w,
                           float* __restrict__ out) {
  size_t i = (size_t)blockIdx.x * 256 + threadIdx.x;
  if (i >= (size_t)47775744ull) return;
  int ow = (int)(i % OHW_); size_t r = i / OHW_;
  int oh = (int)(r % OHW_); r /= OHW_;
  int co = (int)(r % CO_);  int b = (int)(r / CO_);
  const float* xp = x + (size_t)b * CI_ * HW_;
  const float* wp = w + (size_t)co * CI_ * 9;
  float acc = 0.f;
  for (int ci = 0; ci < CI_; ++ci) {
    const float* xr = xp + (size_t)ci * HW_ + oh * H_ + ow;
    const float* wr = wp + ci * 9;
    #pragma unroll
    for (int kh = 0; kh < 3; ++kh)
      #pragma unroll
      for (int kw = 0; kw < 3; ++kw)
        acc += xr[kh * H_ + kw] * wr[kh * 3 + kw];
  }
  out[i] = acc;
}

extern "C" void kernel_launch(void* const* d_in, const int* in_sizes, int n_in,
                              void* d_out, int out_size, void* d_ws, size_t ws_size,
                              hipStream_t stream) {
  const float* x = (const float*)d_in[0];
  const float* w = (const float*)d_in[1];
  float* out = (float*)d_out;

  if (ws_size >= WS_NEED) {
    ushort* xt = (ushort*)d_ws;
    ushort* wt = (ushort*)((char*)d_ws + XT_BYTES);
    transpose_x<<<dim3(49, 32, 2), 256, 0, stream>>>(x, xt);
    repack_w<<<dim3(512), 256, 0, stream>>>(w, wt);
    conv_mfma<<<dim3(NBLK_), 512, 0, stream>>>(xt, wt, out);
  } else {
    naive_conv<<<(47775744 + 255) / 256, 256, 0, stream>>>(x, w, out);
  }
}

// Round 5
// 491.640 us; speedup vs baseline: 1.1325x; 1.0009x over previous
//
#include <hip/hip_runtime.h>

typedef __attribute__((ext_vector_type(8))) short short8;
typedef __attribute__((ext_vector_type(4))) float f32x4;

#define B_    32
#define CI_   256
#define H_    56
#define HW_   3136     // 56*56
#define CO_   512
#define OHW_  54
#define PIXB_ 2916     // 54*54
#define NPIX_ 93312    // 32*2916

// ws layout: x_t bf16 [32][56][56][256]  = 51,380,224 B at offset 0
//            w_t bf16 [9][512][256]      =  2,359,296 B at offset 51,380,224
#define XT_BYTES 51380224ull
#define WS_NEED  53739520ull

__device__ __forceinline__ ushort f2bf(float f) {
  unsigned u = __float_as_uint(f);
  unsigned r = (u + 0x7FFFu + ((u >> 16) & 1u)) >> 16;  // RNE
  return (ushort)r;
}

__device__ __forceinline__ void async16(const void* g, void* l) {
  __builtin_amdgcn_global_load_lds(
      (const __attribute__((address_space(1))) unsigned int*)g,
      (__attribute__((address_space(3))) unsigned int*)l, 16, 0, 0);
}

// ---- pre-pass: x [b][ci][h][w] f32 -> x_t [b][h*w][ci] bf16 ------------
// v1 (measured-best): 64hw x 256ci tile, 33KB LDS, 4 blocks/CU.
#define CIP 260
__global__ __launch_bounds__(256)
void transpose_x(const float* __restrict__ x, ushort* __restrict__ xt) {
  __shared__ ushort tile[64 * CIP];              // 33,280 B
  const int b = blockIdx.y, hw0 = blockIdx.x * 64;
  const int t = threadIdx.x;
  const int j = t & 15, q = t >> 4;              // j: hw4 group, q: ci4 group
  const int hw4 = j * 4;
  const float* xb = x + (size_t)b * CI_ * HW_ + hw0;

  #pragma unroll
  for (int p = 0; p < 4; ++p) {                  // 64 ci per pass
    const int c0 = p * 64 + q * 4;
    float4 v[4];
    #pragma unroll
    for (int r = 0; r < 4; ++r)
      v[r] = *(const float4*)(xb + (size_t)(c0 + r) * HW_ + hw4);
    #pragma unroll
    for (int r2 = 0; r2 < 4; ++r2) {             // r2 = hw offset
      ushort4 o;
      o.x = f2bf(((const float*)&v[0])[r2]);
      o.y = f2bf(((const float*)&v[1])[r2]);
      o.z = f2bf(((const float*)&v[2])[r2]);
      o.w = f2bf(((const float*)&v[3])[r2]);
      *(ushort4*)&tile[(hw4 + r2) * CIP + c0] = o;   // b64, conflict-free
    }
  }
  __syncthreads();

  ushort* ob = xt + ((size_t)b * HW_ + hw0) * CI_;
  #pragma unroll
  for (int p = 0; p < 8; ++p) {
    const int hw  = p * 8 + (t >> 5);
    const int ci8 = (t & 31) * 8;
    const ushort* src = &tile[hw * CIP + ci8];
    uint2 lo = *(const uint2*)src;
    uint2 hi = *(const uint2*)(src + 4);
    uint4 v; v.x = lo.x; v.y = lo.y; v.z = hi.x; v.w = hi.y;
    *(uint4*)(ob + (size_t)hw * CI_ + ci8) = v;  // 16B coalesced
  }
}

// ---- pre-pass: w [co][ci][kh][kw] f32 -> w_t [khkw][co][ci] bf16 -------
__global__ __launch_bounds__(256)
void repack_w(const float* __restrict__ w, ushort* __restrict__ wt) {
  __shared__ float buf[2304];
  const int co = blockIdx.x, t = threadIdx.x;
  const float* wp = w + (size_t)co * 2304;
  #pragma unroll
  for (int p = 0; p < 9; ++p) buf[p * 256 + t] = wp[p * 256 + t];
  __syncthreads();
  #pragma unroll
  for (int k = 0; k < 9; ++k)
    wt[(size_t)k * CO_ * CI_ + (size_t)co * CI_ + t] = f2bf(buf[t * 9 + k]);
}

// ---- main: implicit GEMM, 256co x 128pix tile, BK=64, 8 waves ----------
// Counted-vmcnt triple-buffered pipeline; ONE barrier per K-step; WAVE
// STAGGER: odd waves run the two k-phases in reverse order so at any
// instant ~half the waves feed the LDS port while the other half occupy
// the MFMA pipes (lockstep read-burst/MFMA-burst alternation removed).
#define NT_    36
#define BUFSZ_ 49152          // A 32KB + B 16KB
#define BOFF_  32768
#define NBLK_  1458           // 729 pixel strips x 2 co halves

__global__ __launch_bounds__(512, 2)
void conv_mfma(const ushort* __restrict__ xt, const ushort* __restrict__ wt,
               float* __restrict__ out) {
  __shared__ __align__(128) char lds[3 * BUFSZ_];   // 144 KiB, 1 block/CU

  const int tid  = threadIdx.x;
  const int l    = tid & 63;
  const int wv   = tid >> 6;
  const int quad = l >> 4;
  const int l16  = l & 15;
  const int lr   = l >> 3;          // row-within-8 for staging
  const int lc   = l & 7;           // 16B chunk within 128B row
  const int cswz = (lc ^ lr) << 3;  // ushort offset: inverse-swizzled source

  // bijective XCD chunking (m204; nwg=1458 -> q=182,r=2), co-fastest inside
  const int q8 = 182, r8 = 2;
  const int xcd = blockIdx.x & 7;
  const int idx = blockIdx.x >> 3;
  const int logical =
      (xcd < r8 ? xcd * (q8 + 1) : r8 * (q8 + 1) + (xcd - r8) * q8) + idx;
  const int co0 = (logical & 1) << 8;     // 0 or 256
  const int P0  = (logical >> 1) << 7;    // pixel strip * 128

  // staging source bases (per-thread constants)
  const size_t wbaseA = (size_t)(co0 + wv * 8 + lr) * CI_ + cswz;
  size_t xbase[2];
  #pragma unroll
  for (int r = 0; r < 2; ++r) {
    int P = P0 + r * 64 + wv * 8 + lr;
    int b = P / PIXB_; int rem = P - b * PIXB_;
    int oh = rem / OHW_; int ow = rem - oh * OHW_;
    xbase[r] = ((size_t)b * HW_ + oh * H_ + ow) * CI_ + cswz;
  }

  // fragment read offsets: physical = logical ^ ((row&7)<<4); row&7 == l16&7
  const int wm  = (wv & 3) << 6;    // co offset in 256
  const int wn  = (wv >> 2) << 6;   // pix offset in 128
  const int sA0 = (quad << 4) ^ ((l16 & 7) << 4);
  int raoff[4], rboff[4];
  #pragma unroll
  for (int i = 0; i < 4; ++i) {
    raoff[i] = (wm + i * 16 + l16) * 128 + sA0;
    rboff[i] = BOFF_ + (wn + i * 16 + l16) * 128 + sA0;
  }

  f32x4 acc[4][4];
  #pragma unroll
  for (int i = 0; i < 4; ++i)
    #pragma unroll
    for (int j = 0; j < 4; ++j) acc[i][j] = (f32x4){0.f, 0.f, 0.f, 0.f};

  // stage helpers: tile tt -> buffer buf. A: rounds r0,r0+1; B: round r.
  auto issueA2 = [&](int buf, int tt, int r0) {
    const int k2 = tt >> 2; const int c2 = (tt & 3) << 6;
    const ushort* src = wt + (size_t)k2 * (CO_ * CI_) + wbaseA + c2;
    char* dst = lds + buf * BUFSZ_ + wv * 1024;
    async16(src + (size_t)(r0 << 6) * CI_,       dst + r0 * 8192);
    async16(src + (size_t)((r0 + 1) << 6) * CI_, dst + (r0 + 1) * 8192);
  };
  auto issueB1 = [&](int buf, int tt, int r) {
    const int k2 = tt >> 2; const int c2 = (tt & 3) << 6;
    const int kh2 = k2 / 3, kw2 = k2 - kh2 * 3;
    async16(xt + xbase[r] + (size_t)(kh2 * H_ + kw2) * CI_ + c2,
            lds + buf * BUFSZ_ + BOFF_ + r * 8192 + wv * 1024);
  };

  // prologue: tiles 0,1 fully staged (12 loads/wave in flight)
  issueA2(0, 0, 0); issueA2(0, 0, 2); issueB1(0, 0, 0); issueB1(0, 0, 1);
  issueA2(1, 1, 0); issueA2(1, 1, 2); issueB1(1, 1, 0); issueB1(1, 1, 1);

  int cur = 0;
  for (int t = 0; t < NT_; ++t) {
    // tile t's 6 loads landed; tile t+1's 6 may stay in flight
    if (t == NT_ - 1) asm volatile("s_waitcnt vmcnt(0)" ::: "memory");
    else              asm volatile("s_waitcnt vmcnt(6)" ::: "memory");
    __builtin_amdgcn_sched_barrier(0);     // pin: nothing crosses the wait
    __builtin_amdgcn_s_barrier();          // buf[cur] visible; prev reads done
    asm volatile("" ::: "memory");

    const char* ab  = lds + cur * BUFSZ_;
    const int ibuf  = (cur == 0) ? 2 : cur - 1;   // (t+2) % 3
    const bool pf   = (t < NT_ - 2);

    // one k-phase (xo = 0 or 64); 'first' phase issues staging batch 0
    auto do_phase = [&](int xo, int first) {
      short8 af[4], bfr[4];
      #pragma unroll
      for (int i = 0; i < 4; ++i) {
        af[i]  = *(const short8*)(ab + (raoff[i] ^ xo));
        bfr[i] = *(const short8*)(ab + (rboff[i] ^ xo));
      }
      if (pf) {
        if (first) { issueA2(ibuf, t + 2, 0); issueB1(ibuf, t + 2, 0); }
        else       { issueA2(ibuf, t + 2, 2); issueB1(ibuf, t + 2, 1); }
      }
      __builtin_amdgcn_s_setprio(1);
      #pragma unroll
      for (int mt = 0; mt < 4; ++mt)
        #pragma unroll
        for (int nt = 0; nt < 4; ++nt)
          acc[mt][nt] = __builtin_amdgcn_mfma_f32_16x16x32_bf16(
              af[mt], bfr[nt], acc[mt][nt], 0, 0, 0);
      __builtin_amdgcn_s_setprio(0);
    };

    if (wv & 1) { do_phase(64, 1); do_phase(0, 0); }   // odd: k-hi first
    else        { do_phase(0, 1);  do_phase(64, 0); }  // even: k-lo first

    cur = (cur == 2) ? 0 : cur + 1;
  }

  // epilogue: D row = co (quad*4+reg), col = pixel (lane&15)
  #pragma unroll
  for (int nt = 0; nt < 4; ++nt) {
    int P = P0 + wn + nt * 16 + l16;
    int b = P / PIXB_; int rem = P - b * PIXB_;
    size_t obase = (size_t)b * (CO_ * PIXB_) + rem;
    #pragma unroll
    for (int mt = 0; mt < 4; ++mt) {
      int cobase = co0 + wm + mt * 16 + quad * 4;
      #pragma unroll
      for (int r = 0; r < 4; ++r)
        out[obase + (size_t)(cobase + r) * PIXB_] = acc[mt][nt][r];
    }
  }
}

// ---- fallback: direct conv (only if ws too small) ----------------------
__global__ void naive_conv(const float* __restrict__ x, const float* __restrict__ w,
                           float* __restrict__ out) {
  size_t i = (size_t)blockIdx.x * 256 + threadIdx.x;
  if (i >= (size_t)47775744ull) return;
  int ow = (int)(i % OHW_); size_t r = i / OHW_;
  int oh = (int)(r % OHW_); r /= OHW_;
  int co = (int)(r % CO_);  int b = (int)(r / CO_);
  const float* xp = x + (size_t)b * CI_ * HW_;
  const float* wp = w + (size_t)co * CI_ * 9;
  float acc = 0.f;
  for (int ci = 0; ci < CI_; ++ci) {
    const float* xr = xp + (size_t)ci * HW_ + oh * H_ + ow;
    const float* wr = wp + ci * 9;
    #pragma unroll
    for (int kh = 0; kh < 3; ++kh)
      #pragma unroll
      for (int kw = 0; kw < 3; ++kw)
        acc += xr[kh * H_ + kw] * wr[kh * 3 + kw];
  }
  out[i] = acc;
}

extern "C" void kernel_launch(void* const* d_in, const int* in_sizes, int n_in,
                              void* d_out, int out_size, void* d_ws, size_t ws_size,
                              hipStream_t stream) {
  const float* x = (const float*)d_in[0];
  const float* w = (const float*)d_in[1];
  float* out = (float*)d_out;

  if (ws_size >= WS_NEED) {
    ushort* xt = (ushort*)d_ws;
    ushort* wt = (ushort*)((char*)d_ws + XT_BYTES);
    transpose_x<<<dim3(49, 32), 256, 0, stream>>>(x, xt);
    repack_w<<<dim3(512), 256, 0, stream>>>(w, wt);
    conv_mfma<<<dim3(NBLK_), 512, 0, stream>>>(xt, wt, out);
  } else {
    naive_conv<<<(47775744 + 255) / 256, 256, 0, stream>>>(x, w, out);
  }
}